// Round 7
// baseline (190.254 us; speedup 1.0000x reference)
//
#include <hip/hip_runtime.h>

// Problem constants
#define VV 50000
#define EE 512       // embedding dim (= GEMM K per half; also BYTES/row in fp8)
#define SS 1024      // conv filters (= GEMM N)
#define BB 64
#define LL 256
#define NTOK (BB*LL)         // 16384 token rows (GEMM M)
#define XROWS_PAD (NTOK + 8) // padded rows so last-tile staging never faults

// MX scales: X quantized as x*2^6, W as w*2^5; HW dequant via E8M0 block scales.
// E8M0 byte = 127 + log2(scale): 2^-6 -> 121 (0x79), 2^-5 -> 122 (0x7A).
#define SCALE_A 0x79797979
#define SCALE_B 0x7A7A7A7A

typedef __attribute__((ext_vector_type(8))) int i32x8;
typedef __attribute__((ext_vector_type(16))) float f32x16;

static __device__ __forceinline__ void glds16(const void* g, void* l) {
    __builtin_amdgcn_global_load_lds(
        (const __attribute__((address_space(1))) unsigned int*)g,
        (__attribute__((address_space(3))) unsigned int*)l,
        16, 0, 0);
}

// pack 8 floats (scaled) -> 8 fp8 e4m3 bytes (2 dwords)
static __device__ __forceinline__ uint2 pack8_fp8(float4 v0, float4 v1, float s) {
    int r0 = __builtin_amdgcn_cvt_pk_fp8_f32(v0.x * s, v0.y * s, 0, 0);
    r0 = __builtin_amdgcn_cvt_pk_fp8_f32(v0.z * s, v0.w * s, r0, 1);
    int r1 = __builtin_amdgcn_cvt_pk_fp8_f32(v1.x * s, v1.y * s, 0, 0);
    r1 = __builtin_amdgcn_cvt_pk_fp8_f32(v1.z * s, v1.w * s, r1, 1);
    uint2 o; o.x = (unsigned)r0; o.y = (unsigned)r1; return o;
}

// load one 32-byte fragment (8 dwords) from two swizzled 16B chunks of one row
static __device__ __forceinline__ i32x8 ldfrag(const unsigned char* rowbase, int c0, int c1) {
    const uint4 lo = *(const uint4*)(rowbase + c0 * 16);
    const uint4 hi = *(const uint4*)(rowbase + c1 * 16);
    i32x8 f;
    f[0] = lo.x; f[1] = lo.y; f[2] = lo.z; f[3] = lo.w;
    f[4] = hi.x; f[5] = hi.y; f[6] = hi.z; f[7] = hi.w;
    return f;
}

// Kernel 1 (prep): blocks 0..4095   -> embedding gather, fp32->fp8 (x2^6)
//                  blocks 4096..4607 -> Wc fp32->fp8 (x2^5); block 4096 also
//                  zeroes the per-batch completion counters (ws is poisoned).
__global__ __launch_bounds__(256)
void prep_kernel(const int* __restrict__ inputs,
                 const float* __restrict__ emb,
                 const float* __restrict__ Wc,
                 unsigned char* __restrict__ Xq,
                 unsigned char* __restrict__ Wq,
                 int* __restrict__ cnt) {
    const int tid = threadIdx.x;
    if (blockIdx.x < 4096) {
        const int t = blockIdx.x * 4 + (tid >> 6);
        const int lane = tid & 63;
        const int idx = inputs[t];
        const float* src = emb + (size_t)idx * EE + lane * 8;
        const float4 v0 = *(const float4*)src;
        const float4 v1 = *(const float4*)(src + 4);
        *(uint2*)(Xq + (size_t)t * EE + lane * 8) = pack8_fp8(v0, v1, 64.0f);
    } else {
        const int bb = blockIdx.x - 4096;   // 0..511
        const int i = (bb * 256 + tid) * 8;
        const float4 v0 = *(const float4*)(Wc + i);
        const float4 v1 = *(const float4*)(Wc + i + 4);
        *(uint2*)(Wq + i) = pack8_fp8(v0, v1, 32.0f);
        if (bb == 0 && tid < BB) cnt[tid] = 0;   // kernel-boundary flush -> visible
    }
}

// Kernel 2: fused dual-half MX-fp8 GEMM + sliding-window add + max-pool +
// sigmoid + (last-block-per-batch) classifier + log_softmax.
// conv[t,s] = X[t]·Wc[s,0:512] + X[t+1]·Wc[s,512:1024]  (valid when (t&255)!=255)
// MFMA: mfma_scale_f32_32x32x64_f8f6f4 (K=64 = 2 MX blocks).
// Tile TM=256 (one full batch row -> max-pool completes in-block) x TN=128,
// BK=128 B, 4 kt. Grid 64x8 = 512 blocks = 2/CU, one generation.
// 4 waves 2x2; wave tile 128x64 = 4 row-tiles x 2 col-tiles of 32x32,
// acc f32x16[4][2] (128 VGPR). 48 ds_read_b128 + 32 MFMA per kt per wave.
// Completion: each block sc1-stores its 128 sigmoid outputs, agent fetch_add
// on cnt[b]; the 8th block re-reads pre[b,:] with relaxed agent loads (per-load
// MALL coherence, no L2 invalidate) and runs the 50x1024 classifier tail.
__global__ __launch_bounds__(256, 2)
void conv_gemm_kernel(const unsigned char* __restrict__ Xq,
                      const unsigned char* __restrict__ Wq,
                      float* __restrict__ pre,
                      int* __restrict__ cnt,
                      const float* __restrict__ bc,
                      const float* __restrict__ W1,
                      const float* __restrict__ b1,
                      const float* __restrict__ W2,
                      const float* __restrict__ b2,
                      float* __restrict__ out) {
    __shared__ unsigned char sX[264 * 128];  // rows 0..256 used (+1 for shift)
    __shared__ unsigned char sW[256 * 128];  // [half*128 + s_local][k]
    __shared__ int swin;

    const int tid = threadIdx.x;
    const int w = tid >> 6;          // wave 0..3
    const int lane = tid & 63;
    const int wx = w & 1;            // n-half -> cols wx*64..+64
    const int wy = w >> 1;           // m-half -> rows wy*128..+128
    const int b  = blockIdx.y;       // batch row; m0 = b*256
    const int m0 = b * 256;
    const int s0 = blockIdx.x * 128; // filter-tile base

    f32x16 acc[4][2];
    #pragma unroll
    for (int rt = 0; rt < 4; ++rt)
        #pragma unroll
        for (int nt = 0; nt < 2; ++nt)
            acc[rt][nt] = (f32x16)(0.f);

    const int lrow = lane >> 3;                    // row within 8-row stripe
    const int lcolsw = (((lane & 7) ^ lrow) * 16); // swizzled global col (bytes)
    const int l31 = lane & 31;
    const int lh  = lane >> 5;        // which 32-lane half (k-block select)
    const int sz0 = lane & 7;         // row&7 for unshifted rows
    const int sz1 = (l31 + 1) & 7;    // row&7 for shifted (t+1) rows

    // chunk indices (lane constants): k-step s uses logical chunks s*4+2*lh, +1
    const int cb0 = 2 * lh;          // s=0
    const int cb1 = 4 + 2 * lh;      // s=1

    // row base pointers (kt-invariant)
    const unsigned char* pA0 = sX + (wy * 128 + l31) * 128;      // unshifted
    const unsigned char* pA1 = pA0 + 128;                        // shifted (+1 row)
    const unsigned char* pB1 = sW + (wx * 64 + l31) * 128;       // Wc half 1
    const unsigned char* pB2 = pB1 + 128 * 128;                  // Wc half 2

    #pragma unroll 1
    for (int kt = 0; kt < 4; ++kt) {
        const int k0 = kt * 128;
        // --- stage: X stripes 0..32 (33 KB), W stripes 0..31 (32 KB) ---
        #pragma unroll
        for (int i = 0; i < 8; ++i) {
            const int st = w + 4 * i;                      // 0..31
            glds16(Xq + (size_t)(m0 + st * 8 + lrow) * EE + k0 + lcolsw,
                   (char*)sX + st * 1024);
            const int wrow = st * 8 + lrow;                // 0..255
            const int h = wrow >> 7, sl = wrow & 127;
            glds16(Wq + (size_t)(s0 + sl) * 1024 + h * 512 + k0 + lcolsw,
                   (char*)sW + st * 1024);
        }
        if (w == 0) {   // X rows 256..263 (only 256 used; global side padded)
            glds16(Xq + (size_t)(m0 + 256 + lrow) * EE + k0 + lcolsw,
                   (char*)sX + 32 * 1024);
        }
        __syncthreads();

        // --- compute: preload 8 B frags, then rt-outer (4 A frags + 8 MFMAs) ---
        i32x8 b1f[2][2], b2f[2][2];   // [nt][s]
        #pragma unroll
        for (int nt = 0; nt < 2; ++nt) {
            b1f[nt][0] = ldfrag(pB1 + nt * 4096, cb0 ^ sz0, (cb0 + 1) ^ sz0);
            b1f[nt][1] = ldfrag(pB1 + nt * 4096, cb1 ^ sz0, (cb1 + 1) ^ sz0);
            b2f[nt][0] = ldfrag(pB2 + nt * 4096, cb0 ^ sz0, (cb0 + 1) ^ sz0);
            b2f[nt][1] = ldfrag(pB2 + nt * 4096, cb1 ^ sz0, (cb1 + 1) ^ sz0);
        }
        #pragma unroll
        for (int rt = 0; rt < 4; ++rt) {
            i32x8 a0[2], a1[2];
            a0[0] = ldfrag(pA0 + rt * 4096, cb0 ^ sz0, (cb0 + 1) ^ sz0);
            a0[1] = ldfrag(pA0 + rt * 4096, cb1 ^ sz0, (cb1 + 1) ^ sz0);
            a1[0] = ldfrag(pA1 + rt * 4096, cb0 ^ sz1, (cb0 + 1) ^ sz1);
            a1[1] = ldfrag(pA1 + rt * 4096, cb1 ^ sz1, (cb1 + 1) ^ sz1);
            #pragma unroll
            for (int s = 0; s < 2; ++s)
                #pragma unroll
                for (int nt = 0; nt < 2; ++nt) {
                    acc[rt][nt] = __builtin_amdgcn_mfma_scale_f32_32x32x64_f8f6f4(
                        a0[s], b1f[nt][s], acc[rt][nt], 0, 0, 0, SCALE_A, 0, SCALE_B);
                    acc[rt][nt] = __builtin_amdgcn_mfma_scale_f32_32x32x64_f8f6f4(
                        a1[s], b2f[nt][s], acc[rt][nt], 0, 0, 0, SCALE_A, 0, SCALE_B);
                }
        }
        __syncthreads();
    }

    // --- epilogue: mask t_local==255, column max, combine wy halves ---
    // C/D layout (32x32): col = lane&31, row = (reg&3) + 8*(reg>>2) + 4*(lane>>5)
    float* smax = (float*)sX;  // reuse: [2][128]
    #pragma unroll
    for (int nt = 0; nt < 2; ++nt) {
        float cmax = -3.4e38f;
        #pragma unroll
        for (int rt = 0; rt < 4; ++rt) {
            #pragma unroll
            for (int reg = 0; reg < 16; ++reg) {
                const int row = (reg & 3) + 8 * (reg >> 2) + 4 * lh;
                const int tl = wy * 128 + rt * 32 + row;   // token within batch
                const float v = acc[rt][nt][reg];
                cmax = (tl != 255) ? fmaxf(cmax, v) : cmax;
            }
        }
        cmax = fmaxf(cmax, __shfl_xor(cmax, 32));
        if (lane < 32) smax[wy * 128 + wx * 64 + nt * 32 + lane] = cmax;
    }
    __syncthreads();
    if (tid < 128) {  // pool complete for (b, s0+tid): bias + sigmoid, sc1 store
        const float x = fmaxf(smax[tid], smax[128 + tid]) + bc[s0 + tid];
        const float sig = 1.0f / (1.0f + __expf(-x));
        __hip_atomic_store(&pre[b * SS + s0 + tid], sig,
                           __ATOMIC_RELAXED, __HIP_MEMORY_SCOPE_AGENT);
    }
    __syncthreads();
    if (tid == 0) {
        const int old = __hip_atomic_fetch_add(&cnt[b], 1,
                            __ATOMIC_ACQ_REL, __HIP_MEMORY_SCOPE_AGENT);
        swin = (old == 7);
    }
    __syncthreads();
    if (!swin) return;

    // --- classifier tail (one block per batch): h = sig·W1^T + b1 -> logits ---
    float* ssig = (float*)sX;          // 4 KB
    float* sh   = (float*)(sX + 4096); // 64 floats
    #pragma unroll
    for (int i = 0; i < 4; ++i) {
        const int s = tid + i * 256;
        ssig[s] = __hip_atomic_load(&pre[b * SS + s],
                                    __ATOMIC_RELAXED, __HIP_MEMORY_SCOPE_AGENT);
    }
    if (tid >= 50 && tid < 64) sh[tid] = 0.f;
    __syncthreads();
    const float4* sp = (const float4*)ssig;  // 256 float4
    for (int j = w; j < 50; j += 4) {
        const float4* wp = (const float4*)(W1 + j * SS);
        float p = 0.f;
        #pragma unroll
        for (int i = 0; i < 4; ++i) {
            const float4 a = sp[lane + i * 64];
            const float4 g = wp[lane + i * 64];
            p += a.x * g.x + a.y * g.y + a.z * g.z + a.w * g.w;
        }
        #pragma unroll
        for (int off = 32; off; off >>= 1) p += __shfl_xor(p, off);
        if (lane == 0) sh[j] = p + b1[j];
    }
    __syncthreads();
    if (w == 0) {
        const float hj = (lane < 50) ? sh[lane] : 0.f;
        const float w2a = (lane < 50) ? W2[lane] : 0.f;
        const float w2b = (lane < 50) ? W2[50 + lane] : 0.f;
        float l0 = hj * w2a, l1 = hj * w2b;
        #pragma unroll
        for (int off = 32; off; off >>= 1) {
            l0 += __shfl_xor(l0, off);
            l1 += __shfl_xor(l1, off);
        }
        if (lane == 0) {
            l0 += b2[0]; l1 += b2[1];
            const float m = fmaxf(l0, l1);
            const float lse = m + logf(expf(l0 - m) + expf(l1 - m));
            out[b * 2 + 0] = l0 - lse;
            out[b * 2 + 1] = l1 - lse;
        }
    }
}

extern "C" void kernel_launch(void* const* d_in, const int* in_sizes, int n_in,
                              void* d_out, int out_size, void* d_ws, size_t ws_size,
                              hipStream_t stream) {
    const int*   inputs = (const int*)  d_in[0];
    const float* emb    = (const float*)d_in[1];
    const float* Wc     = (const float*)d_in[2];
    const float* bc     = (const float*)d_in[3];
    const float* W1     = (const float*)d_in[4];
    const float* b1     = (const float*)d_in[5];
    const float* W2     = (const float*)d_in[6];
    const float* b2     = (const float*)d_in[7];
    float* out = (float*)d_out;

    // ws layout
    unsigned char* Xq = (unsigned char*)d_ws;                    // XROWS_PAD*512 fp8
    unsigned char* Wq = Xq + (size_t)XROWS_PAD * EE;             // 1024*1024 fp8
    float*         pre = (float*)(Wq + (size_t)SS * 1024);       // 64*1024 f32
    int*           cnt = (int*)(pre + (size_t)BB * SS);          // 64 ints

    prep_kernel<<<4608, 256, 0, stream>>>(inputs, emb, Wc, Xq, Wq, cnt);
    dim3 grid(SS / 128, NTOK / 256);  // (8, 64) = 512 blocks, 2/CU exactly
    conv_gemm_kernel<<<grid, 256, 0, stream>>>(Xq, Wq, pre, cnt,
                                               bc, W1, b1, W2, b2, out);
}

// Round 8
// 179.586 us; speedup vs baseline: 1.0594x; 1.0594x over previous
//
#include <hip/hip_runtime.h>

// Problem constants
#define VV 50000
#define EE 512       // embedding dim (= GEMM K per half; also BYTES/row in fp8)
#define SS 1024      // conv filters (= GEMM N)
#define BB 64
#define LL 256
#define NTOK (BB*LL)         // 16384 token rows (GEMM M)
#define XROWS_PAD (NTOK + 8) // padded rows so last-tile staging never faults

// MX scales: X quantized as x*2^6, W as w*2^5; HW dequant via E8M0 block scales.
// E8M0 byte = 127 + log2(scale): 2^-6 -> 121 (0x79), 2^-5 -> 122 (0x7A).
#define SCALE_A 0x79797979
#define SCALE_B 0x7A7A7A7A

typedef __attribute__((ext_vector_type(8))) int i32x8;
typedef __attribute__((ext_vector_type(16))) float f32x16;

static __device__ __forceinline__ void glds16(const void* g, void* l) {
    __builtin_amdgcn_global_load_lds(
        (const __attribute__((address_space(1))) unsigned int*)g,
        (__attribute__((address_space(3))) unsigned int*)l,
        16, 0, 0);
}

// pack 8 floats (scaled) -> 8 fp8 e4m3 bytes (2 dwords)
static __device__ __forceinline__ uint2 pack8_fp8(float4 v0, float4 v1, float s) {
    int r0 = __builtin_amdgcn_cvt_pk_fp8_f32(v0.x * s, v0.y * s, 0, 0);
    r0 = __builtin_amdgcn_cvt_pk_fp8_f32(v0.z * s, v0.w * s, r0, 1);
    int r1 = __builtin_amdgcn_cvt_pk_fp8_f32(v1.x * s, v1.y * s, 0, 0);
    r1 = __builtin_amdgcn_cvt_pk_fp8_f32(v1.z * s, v1.w * s, r1, 1);
    uint2 o; o.x = (unsigned)r0; o.y = (unsigned)r1; return o;
}

// load one 32-byte fragment (8 dwords) from two swizzled 16B chunks of one row
static __device__ __forceinline__ i32x8 ldfrag(const unsigned char* rowbase, int c0, int c1) {
    const uint4 lo = *(const uint4*)(rowbase + c0 * 16);
    const uint4 hi = *(const uint4*)(rowbase + c1 * 16);
    i32x8 f;
    f[0] = lo.x; f[1] = lo.y; f[2] = lo.z; f[3] = lo.w;
    f[4] = hi.x; f[5] = hi.y; f[6] = hi.z; f[7] = hi.w;
    return f;
}

// Kernel 1 (prep): blocks 0..4095   -> embedding gather, fp32->fp8 (x2^6)
//                  blocks 4096..4607 -> Wc fp32->fp8 (x2^5)
__global__ __launch_bounds__(256)
void prep_kernel(const int* __restrict__ inputs,
                 const float* __restrict__ emb,
                 const float* __restrict__ Wc,
                 unsigned char* __restrict__ Xq,
                 unsigned char* __restrict__ Wq) {
    const int tid = threadIdx.x;
    if (blockIdx.x < 4096) {
        const int t = blockIdx.x * 4 + (tid >> 6);
        const int lane = tid & 63;
        const int idx = inputs[t];
        const float* src = emb + (size_t)idx * EE + lane * 8;
        const float4 v0 = *(const float4*)src;
        const float4 v1 = *(const float4*)(src + 4);
        *(uint2*)(Xq + (size_t)t * EE + lane * 8) = pack8_fp8(v0, v1, 64.0f);
    } else {
        const int bb = blockIdx.x - 4096;   // 0..511
        const int i = (bb * 256 + tid) * 8;
        const float4 v0 = *(const float4*)(Wc + i);
        const float4 v1 = *(const float4*)(Wc + i + 4);
        *(uint2*)(Wq + i) = pack8_fp8(v0, v1, 32.0f);
    }
}

// Kernel 2: fused dual-half MX-fp8 GEMM + sliding-window add + max-pool.
// conv[t,s] = X[t]·Wc[s,0:512] + X[t+1]·Wc[s,512:1024]  (valid when (t&255)!=255)
// MFMA: mfma_scale_f32_32x32x64_f8f6f4 (K=64 = 2 MX blocks).
// Tile TM=256 (= ONE FULL BATCH ROW -> max-pool completes in-block, no atomics,
// no pre-init) x TN=128, BK=128 B, 4 kt. Grid 64x8 = 512 blocks = 2/CU exactly.
// 4 waves 2x2; wave tile 128 rows x 64 cols = 4 row-tiles x 2 col-tiles of
// 32x32, acc f32x16[4][2] (128 VGPR). 48 ds_read_b128 + 32 MFMA per kt/wave.
// A/B frag layout (32x32x64): m|n = lane&31, k = (lane>>5)*32 + j.
// LDS: 8-row stripes of 8 16B chunks, XOR swizzle (phys chunk c of row r holds
// logical c^(r&7)) -> conflict-free; glds16 dest = stripe + lane*16.
// NOTE (R7 post-mortem): fusing the classifier tail into this kernel via
// agent-scope atomics + last-block-done REGRESSED +10us (serializes the tail
// onto the GEMM critical path; separate 64-block dispatch overlaps it).
__global__ __launch_bounds__(256, 2)
void conv_gemm_kernel(const unsigned char* __restrict__ Xq,
                      const unsigned char* __restrict__ Wq,
                      float* __restrict__ pre) {
    __shared__ unsigned char sX[264 * 128];  // rows 0..256 used (+1 for shift)
    __shared__ unsigned char sW[256 * 128];  // [half*128 + s_local][k]

    const int tid = threadIdx.x;
    const int w = tid >> 6;          // wave 0..3
    const int lane = tid & 63;
    const int wx = w & 1;            // n-half -> cols wx*64..+64
    const int wy = w >> 1;           // m-half -> rows wy*128..+128
    const int b  = blockIdx.y;       // batch row; m0 = b*256
    const int m0 = b * 256;
    const int s0 = blockIdx.x * 128; // filter-tile base

    f32x16 acc[4][2];
    #pragma unroll
    for (int rt = 0; rt < 4; ++rt)
        #pragma unroll
        for (int nt = 0; nt < 2; ++nt)
            acc[rt][nt] = (f32x16)(0.f);

    const int lrow = lane >> 3;                    // row within 8-row stripe
    const int lcolsw = (((lane & 7) ^ lrow) * 16); // swizzled global col (bytes)
    const int l31 = lane & 31;
    const int lh  = lane >> 5;        // which 32-lane half (k-block select)
    const int sz0 = lane & 7;         // row&7 for unshifted rows
    const int sz1 = (l31 + 1) & 7;    // row&7 for shifted (t+1) rows

    // chunk indices (lane constants): k-step s uses logical chunks s*4+2*lh, +1
    const int cb0 = 2 * lh;          // s=0
    const int cb1 = 4 + 2 * lh;      // s=1

    // row base pointers (kt-invariant)
    const unsigned char* pA0 = sX + (wy * 128 + l31) * 128;      // unshifted
    const unsigned char* pA1 = pA0 + 128;                        // shifted (+1 row)
    const unsigned char* pB1 = sW + (wx * 64 + l31) * 128;       // Wc half 1
    const unsigned char* pB2 = pB1 + 128 * 128;                  // Wc half 2

    #pragma unroll 1
    for (int kt = 0; kt < 4; ++kt) {
        const int k0 = kt * 128;
        // --- stage: X stripes 0..32 (33 KB), W stripes 0..31 (32 KB) ---
        #pragma unroll
        for (int i = 0; i < 8; ++i) {
            const int st = w + 4 * i;                      // 0..31
            glds16(Xq + (size_t)(m0 + st * 8 + lrow) * EE + k0 + lcolsw,
                   (char*)sX + st * 1024);
            const int wrow = st * 8 + lrow;                // 0..255
            const int h = wrow >> 7, sl = wrow & 127;
            glds16(Wq + (size_t)(s0 + sl) * 1024 + h * 512 + k0 + lcolsw,
                   (char*)sW + st * 1024);
        }
        if (w == 0) {   // X rows 256..263 (only 256 used; global side padded)
            glds16(Xq + (size_t)(m0 + 256 + lrow) * EE + k0 + lcolsw,
                   (char*)sX + 32 * 1024);
        }
        __syncthreads();

        // --- compute: preload 8 B frags, then rt-outer (4 A frags + 8 MFMAs) ---
        i32x8 b1[2][2], b2[2][2];   // [nt][s]
        #pragma unroll
        for (int nt = 0; nt < 2; ++nt) {
            b1[nt][0] = ldfrag(pB1 + nt * 4096, cb0 ^ sz0, (cb0 + 1) ^ sz0);
            b1[nt][1] = ldfrag(pB1 + nt * 4096, cb1 ^ sz0, (cb1 + 1) ^ sz0);
            b2[nt][0] = ldfrag(pB2 + nt * 4096, cb0 ^ sz0, (cb0 + 1) ^ sz0);
            b2[nt][1] = ldfrag(pB2 + nt * 4096, cb1 ^ sz0, (cb1 + 1) ^ sz0);
        }
        #pragma unroll
        for (int rt = 0; rt < 4; ++rt) {
            i32x8 a0[2], a1[2];
            a0[0] = ldfrag(pA0 + rt * 4096, cb0 ^ sz0, (cb0 + 1) ^ sz0);
            a0[1] = ldfrag(pA0 + rt * 4096, cb1 ^ sz0, (cb1 + 1) ^ sz0);
            a1[0] = ldfrag(pA1 + rt * 4096, cb0 ^ sz1, (cb0 + 1) ^ sz1);
            a1[1] = ldfrag(pA1 + rt * 4096, cb1 ^ sz1, (cb1 + 1) ^ sz1);
            #pragma unroll
            for (int s = 0; s < 2; ++s)
                #pragma unroll
                for (int nt = 0; nt < 2; ++nt) {
                    acc[rt][nt] = __builtin_amdgcn_mfma_scale_f32_32x32x64_f8f6f4(
                        a0[s], b1[nt][s], acc[rt][nt], 0, 0, 0, SCALE_A, 0, SCALE_B);
                    acc[rt][nt] = __builtin_amdgcn_mfma_scale_f32_32x32x64_f8f6f4(
                        a1[s], b2[nt][s], acc[rt][nt], 0, 0, 0, SCALE_A, 0, SCALE_B);
                }
        }
        __syncthreads();
    }

    // --- epilogue: mask t_local==255, column max, combine wy halves, store ---
    // C/D layout (32x32): col = lane&31, row = (reg&3) + 8*(reg>>2) + 4*(lane>>5)
    float* smax = (float*)sX;  // reuse: [2][128]
    #pragma unroll
    for (int nt = 0; nt < 2; ++nt) {
        float cmax = -3.4e38f;
        #pragma unroll
        for (int rt = 0; rt < 4; ++rt) {
            #pragma unroll
            for (int reg = 0; reg < 16; ++reg) {
                const int row = (reg & 3) + 8 * (reg >> 2) + 4 * lh;
                const int tl = wy * 128 + rt * 32 + row;   // token within batch
                const float v = acc[rt][nt][reg];
                cmax = (tl != 255) ? fmaxf(cmax, v) : cmax;
            }
        }
        cmax = fmaxf(cmax, __shfl_xor(cmax, 32));
        if (lane < 32) smax[wy * 128 + wx * 64 + nt * 32 + lane] = cmax;
    }
    __syncthreads();
    if (tid < 128)  // max-pool complete for this (batch, filter) — direct store
        pre[b * SS + s0 + tid] = fmaxf(smax[tid], smax[128 + tid]);
}

// Kernel 3: sigmoid(max + bc) -> h = sig·W1^T + b1 -> logits -> log_softmax.
__global__ __launch_bounds__(1024)
void classifier_kernel(const float* __restrict__ pre,
                       const float* __restrict__ bc,
                       const float* __restrict__ W1,
                       const float* __restrict__ b1,
                       const float* __restrict__ W2,
                       const float* __restrict__ b2,
                       float* __restrict__ out) {
    __shared__ float ssig[SS];
    __shared__ float sh[64];
    const int b = blockIdx.x;
    const int tid = threadIdx.x;
    {
        const float x = pre[b * SS + tid] + bc[tid];
        ssig[tid] = 1.0f / (1.0f + __expf(-x));
    }
    if (tid >= 50 && tid < 64) sh[tid] = 0.f;
    __syncthreads();
    const int w = tid >> 6, lane = tid & 63;
    const float4* sp = (const float4*)ssig;  // 256 float4
    for (int j = w; j < 50; j += 16) {
        const float4* wp = (const float4*)(W1 + j * SS);
        float p = 0.f;
        #pragma unroll
        for (int i = 0; i < 4; ++i) {
            const float4 a = sp[lane + i * 64];
            const float4 g = wp[lane + i * 64];
            p += a.x * g.x + a.y * g.y + a.z * g.z + a.w * g.w;
        }
        #pragma unroll
        for (int off = 32; off; off >>= 1) p += __shfl_xor(p, off);
        if (lane == 0) sh[j] = p + b1[j];
    }
    __syncthreads();
    if (w == 0) {
        const float hj = (lane < 50) ? sh[lane] : 0.f;
        const float w2a = (lane < 50) ? W2[lane] : 0.f;
        const float w2b = (lane < 50) ? W2[50 + lane] : 0.f;
        float l0 = hj * w2a, l1 = hj * w2b;
        #pragma unroll
        for (int off = 32; off; off >>= 1) {
            l0 += __shfl_xor(l0, off);
            l1 += __shfl_xor(l1, off);
        }
        if (lane == 0) {
            l0 += b2[0]; l1 += b2[1];
            const float m = fmaxf(l0, l1);
            const float lse = m + logf(expf(l0 - m) + expf(l1 - m));
            out[b * 2 + 0] = l0 - lse;
            out[b * 2 + 1] = l1 - lse;
        }
    }
}

extern "C" void kernel_launch(void* const* d_in, const int* in_sizes, int n_in,
                              void* d_out, int out_size, void* d_ws, size_t ws_size,
                              hipStream_t stream) {
    const int*   inputs = (const int*)  d_in[0];
    const float* emb    = (const float*)d_in[1];
    const float* Wc     = (const float*)d_in[2];
    const float* bc     = (const float*)d_in[3];
    const float* W1     = (const float*)d_in[4];
    const float* b1     = (const float*)d_in[5];
    const float* W2     = (const float*)d_in[6];
    const float* b2     = (const float*)d_in[7];
    float* out = (float*)d_out;

    // ws layout
    unsigned char* Xq = (unsigned char*)d_ws;                    // XROWS_PAD*512 fp8
    unsigned char* Wq = Xq + (size_t)XROWS_PAD * EE;             // 1024*1024 fp8
    float*         pre = (float*)(Wq + (size_t)SS * 1024);       // 64*1024 f32

    prep_kernel<<<4608, 256, 0, stream>>>(inputs, emb, Wc, Xq, Wq);
    dim3 grid(SS / 128, NTOK / 256);  // (8, 64) = 512 blocks, 2/CU exactly
    conv_gemm_kernel<<<grid, 256, 0, stream>>>(Xq, Wq, pre);
    classifier_kernel<<<BB, 1024, 0, stream>>>(pre, bc, W1, b1, W2, b2, out);
}